// Round 18
// baseline (831.280 us; speedup 1.0000x reference)
//
#include <hip/hip_runtime.h>
#include <hip/hip_bf16.h>
#include <stdint.h>

#define N_NODES 20000
#define N_EDGES 40000
#define NODE_DIM 5
#define EDGE_DIM 6
#define HID 64
#define N_GRAPHS 500
#define NPG 40
#define TORSIONS 10
#define N_TORS (N_GRAPHS * TORSIONS)
#define ACT 6

typedef short short8 __attribute__((ext_vector_type(8)));
typedef float f32x4 __attribute__((ext_vector_type(4)));

__device__ __forceinline__ float sigmoidf_(float x) { return 1.0f / (1.0f + __expf(-x)); }
__device__ __forceinline__ float dot4(float4 a, float4 b) {
    return a.x * b.x + a.y * b.y + a.z * b.z + a.w * b.w;
}
__device__ __forceinline__ float bf_lo(unsigned int u) {
    union { unsigned int i; float f; } v; v.i = u << 16; return v.f;
}
__device__ __forceinline__ float bf_hi(unsigned int u) {
    union { unsigned int i; float f; } v; v.i = u & 0xffff0000u; return v.f;
}

// ---------------- fused prologue ----------------
#define PR_LIN0   (N_NODES * 64)
#define PR_H1     (N_EDGES * 128)
#define PR_PREP   (4096 * 128)
#define PR_PREP2  (24576 + 4096)
#define PR_PREP3  (192 * 256 + 128 * 256 + 320 * 64)
#define PR_TOTAL  (PR_LIN0 + PR_H1 + PR_PREP + PR_PREP2 + PR_PREP3 + N_NODES)

__global__ __launch_bounds__(256) void k_mega_prep(
    const float* __restrict__ x, const float* __restrict__ lin0_w, const float* __restrict__ lin0_b,
    const float* __restrict__ ea, const float* __restrict__ enn_w1, const float* __restrict__ enn_b1,
    const float* __restrict__ w2, const float* __restrict__ b2,
    const float* __restrict__ cr, const float* __restrict__ gwih, const float* __restrict__ gwhh,
    const float* __restrict__ swih, const float* __restrict__ swhh,
    const float* __restrict__ mwih, const float* __restrict__ mlpw1,
    float* __restrict__ out, __hip_bfloat16* __restrict__ h1b,
    __hip_bfloat16* __restrict__ w2pb, __hip_bfloat16* __restrict__ b2pb,
    __hip_bfloat16* __restrict__ crTb, __hip_bfloat16* __restrict__ wihb,
    __hip_bfloat16* __restrict__ whhb,
    float* __restrict__ wT, float* __restrict__ mT, float* __restrict__ w1T,
    int* __restrict__ degi) {
    int i = blockIdx.x * blockDim.x + threadIdx.x;
    if (i < PR_LIN0) {
        int n = i >> 6, k = i & 63;
        const float* xr = x + n * NODE_DIM;
        const float* wr = lin0_w + k * NODE_DIM;
        float s = lin0_b[k];
#pragma unroll
        for (int d = 0; d < NODE_DIM; ++d) s += xr[d] * wr[d];
        out[i] = fmaxf(s, 0.0f);
        return;
    }
    i -= PR_LIN0;
    if (i < PR_H1) {
        int e = i >> 7, j = i & 127;
        const float* er = ea + e * EDGE_DIM;
        const float* wr = enn_w1 + j * EDGE_DIM;
        float s = enn_b1[j];
#pragma unroll
        for (int d = 0; d < EDGE_DIM; ++d) s += er[d] * wr[d];
        h1b[i] = __float2bfloat16(fmaxf(s, 0.0f));
        return;
    }
    i -= PR_H1;
    if (i < PR_PREP) {
        int cp = i >> 7, j = i & 127;
        int c = ((cp & 63) << 6) | (cp >> 6);
        w2pb[i] = __float2bfloat16(w2[c * 128 + j]);
        if (j == 0) b2pb[cp] = __float2bfloat16(b2[c]);
        return;
    }
    i -= PR_PREP;
    if (i < PR_PREP2) {
        if (i < 12288) {
            wihb[i] = __float2bfloat16(gwih[i]);
        } else if (i < 24576) {
            whhb[i - 12288] = __float2bfloat16(gwhh[i - 12288]);
        } else {
            int t = i - 24576;
            int c = t >> 6, h = t & 63;
            crTb[t] = __float2bfloat16(cr[h * 64 + c]);
        }
        return;
    }
    i -= PR_PREP2;
    if (i < PR_PREP3) {
        if (i < 192 * 256) {
            int k = i >> 8, j = i & 255;
            wT[i] = (k < 128) ? swih[j * 128 + k] : swhh[j * 64 + (k - 128)];
        } else if (i < 192 * 256 + 128 * 256) {
            int t = i - 192 * 256;
            int k = t >> 8, j = t & 255;
            mT[t] = mwih[j * 128 + k];
        } else {
            int t = i - (192 * 256 + 128 * 256);
            int ii = t >> 6, j = t & 63;
            w1T[t] = mlpw1[j * 320 + ii];
        }
        return;
    }
    i -= PR_PREP3;
    if (i < N_NODES) degi[i] = 0;
}

// ---------------- in-degree ----------------
__global__ void k_deg(const int* __restrict__ ei, int* __restrict__ degi) {
    int e = blockIdx.x * blockDim.x + threadIdx.x;
    if (e >= N_EDGES) return;
    atomicAdd(&degi[ei[N_EDGES + e]], 1);
}

// ---------------- exclusive scan ----------------
#define SCAN_C 79
__global__ __launch_bounds__(256) void k_scan(const int* __restrict__ degi,
                                              int* __restrict__ rowptr, int* __restrict__ cursor) {
    __shared__ int part[256];
    int t = threadIdx.x;
    int base = t * SCAN_C;
    int s = 0;
    for (int i = 0; i < SCAN_C; ++i) {
        int idx = base + i;
        if (idx < N_NODES) s += degi[idx];
    }
    part[t] = s;
    __syncthreads();
    for (int off = 1; off < 256; off <<= 1) {
        int v = (t >= off) ? part[t - off] : 0;
        __syncthreads();
        part[t] += v;
        __syncthreads();
    }
    int run = part[t] - s;
    for (int i = 0; i < SCAN_C; ++i) {
        int idx = base + i;
        if (idx < N_NODES) {
            rowptr[idx] = run;
            cursor[idx] = run;
            run += degi[idx];
        }
    }
    if (t == 0) rowptr[N_NODES] = N_EDGES;
}

// ---------------- CSR fill ----------------
__global__ void k_fill(const int* __restrict__ ei, int* __restrict__ cursor,
                       int* __restrict__ csr) {
    int e = blockIdx.x * blockDim.x + threadIdx.x;
    if (e >= N_EDGES) return;
    int d = ei[N_EDGES + e];
    int pos = atomicAdd(&cursor[d], 1);
    csr[pos] = e;
}

// ---------------- edge messages: 256-thread blocks (4 waves), wave owns 2 kt -> 8 kt/block ----------------
// 4x more independent barrier domains per CU than round 17 (same per-wave math).
// kb in 0..7; grid = 1024: xg = bid&7 -> XCD; kb = (bid>>3)&7; ebg = (bid>>6)*8 + xg (guard >=125).
// LDS ~38 KB -> 3-4 blocks/CU. Sync staging; LDS-staged 32-B coop stores (round-16 pattern).
#define EPB 5
__global__ __launch_bounds__(256) void k_edge_msg(
    const int* __restrict__ ei, const float* __restrict__ out,
    const __hip_bfloat16* __restrict__ h1b, const __hip_bfloat16* __restrict__ w2pb,
    const __hip_bfloat16* __restrict__ b2pb, float* __restrict__ msg) {
    __shared__ __align__(16) short aS[64 * 17 * 8];   // h1 rows, stride 17 short8 (17.4 KB)
    __shared__ __align__(16) float oS[64 * 68];       // o rows, stride 68 f32 (17.4 KB)
    __shared__ __align__(16) float mS[64 * 9];        // msg tile 64e x 8kt, stride 9 (2.3 KB)
    __shared__ __align__(8)  short bS[512];           // bias slice for this kb (1 KB)
    int bid = blockIdx.x;
    int xg = bid & 7, kb = (bid >> 3) & 7, eg = bid >> 6;
    int ebg = eg * 8 + xg;          // 0..127; guard
    if (ebg >= 125) return;
    int tid = threadIdx.x, w = tid >> 6, lane = tid & 63;
    int lm = lane & 15, lk = lane >> 4;
    const short8* W8 = (const short8*)w2pb;
    short8 afr[2][4][4];
#pragma unroll
    for (int u = 0; u < 2; ++u)
#pragma unroll
        for (int hi = 0; hi < 4; ++hi)
#pragma unroll
            for (int ks = 0; ks < 4; ++ks)
                afr[u][hi][ks] = W8[(size_t)(((kb << 3) + (w << 1) + u) * 64 + hi * 16 + lm) * 16 + ks * 4 + lk];
    bS[tid] = ((const short*)b2pb)[(kb << 9) + tid];
    bS[tid + 256] = ((const short*)b2pb)[(kb << 9) + tid + 256];
    const short8* aSb8 = (const short8*)aS;
    const float4* oS4 = (const float4*)oS;
    for (int t = 0; t < EPB; ++t) {
        int e0 = (ebg * EPB + t) << 6;
        {   // stage h1: 64 rows x 16 uint4, 4 per thread
            const uint4* g = (const uint4*)(h1b + (size_t)e0 * 128);
            uint4* s = (uint4*)aS;
#pragma unroll
            for (int p = 0; p < 4; ++p) {
                int i = tid + 256 * p;
                s[(i >> 4) * 17 + (i & 15)] = g[i];
            }
        }
        {   // gather out[src]: 64 rows x 16 float4, 4 per thread
            const float4* og = (const float4*)out;
            float4* s = (float4*)oS;
#pragma unroll
            for (int p = 0; p < 4; ++p) {
                int i = tid + 256 * p;
                int src = ei[e0 + (i >> 4)];
                s[(i >> 4) * 17 + (i & 15)] = og[(size_t)src * 16 + (i & 15)];
            }
        }
        __syncthreads();
#pragma unroll
        for (int ee = 0; ee < 4; ++ee) {
            short8 bfr[4];
#pragma unroll
            for (int ks = 0; ks < 4; ++ks) bfr[ks] = aSb8[(ee * 16 + lm) * 17 + ks * 4 + lk];
            float4 ofr[4];
#pragma unroll
            for (int hi = 0; hi < 4; ++hi) ofr[hi] = oS4[(ee * 16 + lm) * 17 + hi * 4 + lk];
            float pk[2] = {0.0f, 0.0f};
#pragma unroll
            for (int u = 0; u < 2; ++u) {
#pragma unroll
                for (int hi = 0; hi < 4; ++hi) {
                    f32x4 a0 = (f32x4){0.f, 0.f, 0.f, 0.f};
                    f32x4 a1 = (f32x4){0.f, 0.f, 0.f, 0.f};
                    a0 = __builtin_amdgcn_mfma_f32_16x16x32_bf16(afr[u][hi][0], bfr[0], a0, 0, 0, 0);
                    a1 = __builtin_amdgcn_mfma_f32_16x16x32_bf16(afr[u][hi][1], bfr[1], a1, 0, 0, 0);
                    a0 = __builtin_amdgcn_mfma_f32_16x16x32_bf16(afr[u][hi][2], bfr[2], a0, 0, 0, 0);
                    a1 = __builtin_amdgcn_mfma_f32_16x16x32_bf16(afr[u][hi][3], bfr[3], a1, 0, 0, 0);
                    uint2 bp = *(const uint2*)(bS + ((w << 1) + u) * 64 + hi * 16 + lk * 4);
                    pk[u] += (a0[0] + a1[0] + bf_lo(bp.x)) * ofr[hi].x +
                             (a0[1] + a1[1] + bf_hi(bp.x)) * ofr[hi].y +
                             (a0[2] + a1[2] + bf_lo(bp.y)) * ofr[hi].z +
                             (a0[3] + a1[3] + bf_hi(bp.y)) * ofr[hi].w;
                }
                pk[u] += __shfl_xor(pk[u], 16);
                pk[u] += __shfl_xor(pk[u], 32);
            }
            if (lane < 16) {
                mS[(ee * 16 + lane) * 9 + (w << 1)]     = pk[0];
                mS[(ee * 16 + lane) * 9 + (w << 1) + 1] = pk[1];
            }
        }
        __syncthreads();
        {   // cooperative store: 64 edges x 8 kt, 2 per thread; 8 threads = 32 B contiguous
#pragma unroll
            for (int p = 0; p < 2; ++p) {
                int idx = tid + 256 * p;
                int e = idx >> 3, kl = idx & 7;
                msg[(size_t)(e0 + e) * 64 + (kb << 3) + kl] = mS[e * 9 + kl];
            }
        }
    }
}

// ---------------- fused node update: CSR-agg + root GEMM + m + GRU; 1 wave = 16 nodes ----------------
__global__ __launch_bounds__(64) void k_node_fused(
    float* __restrict__ out,
    const int* __restrict__ rowptr, const int* __restrict__ csr, const float* __restrict__ msg,
    const __hip_bfloat16* __restrict__ crTb, const float* __restrict__ cb,
    const __hip_bfloat16* __restrict__ wihb, const __hip_bfloat16* __restrict__ whhb,
    const float* __restrict__ bih, const float* __restrict__ bhh) {
    __shared__ __align__(16) float Xf[16 * 68];
    __shared__ __align__(16) short Xb[16 * 72];
    __shared__ __align__(16) short Mb[16 * 72];
    int n0 = blockIdx.x << 4;
    int lane = threadIdx.x;
    {
        int r = lane >> 2, q = lane & 3;
        const float4* gv = (const float4*)(out + (size_t)(n0 + r) * 64);
        float4 v[4];
#pragma unroll
        for (int i = 0; i < 4; ++i) v[i] = gv[q * 4 + i];
        float4* sv = (float4*)Xf;
#pragma unroll
        for (int i = 0; i < 4; ++i) sv[r * 17 + q * 4 + i] = v[i];
        __hip_bfloat16* xb = (__hip_bfloat16*)Xb;
        const float* vf = (const float*)v;
#pragma unroll
        for (int i = 0; i < 16; ++i) xb[r * 72 + q * 16 + i] = __float2bfloat16(vf[i]);
    }
    __syncthreads();
    int lm = lane & 15, lk = lane >> 4;
    const short8* Xb8 = (const short8*)Xb;
    short8 ax[2];
#pragma unroll
    for (int ks = 0; ks < 2; ++ks) ax[ks] = Xb8[lm * 9 + ks * 4 + lk];
    const short8* Bc = (const short8*)crTb;
    f32x4 accr[4];
#pragma unroll
    for (int ci = 0; ci < 4; ++ci) accr[ci] = (f32x4){0.f, 0.f, 0.f, 0.f};
#pragma unroll
    for (int ks = 0; ks < 2; ++ks)
#pragma unroll
        for (int ci = 0; ci < 4; ++ci) {
            short8 b = Bc[(ci * 16 + lm) * 8 + ks * 4 + lk];
            accr[ci] = __builtin_amdgcn_mfma_f32_16x16x32_bf16(ax[ks], b, accr[ci], 0, 0, 0);
        }
    float aost[4][4];  // [j][ci]
#pragma unroll
    for (int j = 0; j < 4; ++j) {
        int n = n0 + lk * 4 + j;
        int b = rowptr[n], e_ = rowptr[n + 1];
        float s0 = 0.f, s1 = 0.f, s2 = 0.f, s3 = 0.f;
        for (int i = b; i < e_; ++i) {
            const float* mrow = msg + (size_t)csr[i] * 64;
            s0 += mrow[lm];
            s1 += mrow[16 + lm];
            s2 += mrow[32 + lm];
            s3 += mrow[48 + lm];
        }
        float inv = 1.0f / fmaxf((float)(e_ - b), 1.0f);
        aost[j][0] = s0 * inv; aost[j][1] = s1 * inv; aost[j][2] = s2 * inv; aost[j][3] = s3 * inv;
    }
    __hip_bfloat16* mb = (__hip_bfloat16*)Mb;
#pragma unroll
    for (int ci = 0; ci < 4; ++ci) {
        int col = ci * 16 + lm;
        float cbv = cb[col];
#pragma unroll
        for (int j = 0; j < 4; ++j) {
            int row = lk * 4 + j;
            float m = fmaxf(aost[j][ci] + accr[ci][j] + cbv, 0.f);
            mb[row * 72 + col] = __float2bfloat16(m);
        }
    }
    __syncthreads();
    short8 am[2];
#pragma unroll
    for (int ks = 0; ks < 2; ++ks) am[ks] = ((const short8*)Mb)[lm * 9 + ks * 4 + lk];
    const short8* Bi = (const short8*)wihb;
    const short8* Bh = (const short8*)whhb;
    f32x4 gi[12], gh[12];
#pragma unroll
    for (int ci = 0; ci < 12; ++ci) {
        gi[ci] = (f32x4){0.f, 0.f, 0.f, 0.f};
        gh[ci] = (f32x4){0.f, 0.f, 0.f, 0.f};
    }
#pragma unroll
    for (int ks = 0; ks < 2; ++ks)
#pragma unroll
        for (int ci = 0; ci < 12; ++ci) {
            short8 bi = Bi[(ci * 16 + lm) * 8 + ks * 4 + lk];
            short8 bh = Bh[(ci * 16 + lm) * 8 + ks * 4 + lk];
            gi[ci] = __builtin_amdgcn_mfma_f32_16x16x32_bf16(am[ks], bi, gi[ci], 0, 0, 0);
            gh[ci] = __builtin_amdgcn_mfma_f32_16x16x32_bf16(ax[ks], bh, gh[ci], 0, 0, 0);
        }
#pragma unroll
    for (int ci = 0; ci < 4; ++ci) {
        int col = ci * 16 + lm;
        float bir = bih[col], biz = bih[64 + col], bin = bih[128 + col];
        float bhr = bhh[col], bhz = bhh[64 + col], bhn = bhh[128 + col];
#pragma unroll
        for (int j = 0; j < 4; ++j) {
            int row = lk * 4 + j;
            int n = n0 + row;
            float r = sigmoidf_(gi[ci][j] + bir + gh[ci][j] + bhr);
            float z = sigmoidf_(gi[ci + 4][j] + biz + gh[ci + 4][j] + bhz);
            float nn = tanhf(gi[ci + 8][j] + bin + r * (gh[ci + 8][j] + bhn));
            float hold = Xf[row * 68 + col];
            out[(size_t)n * 64 + col] = (1.f - z) * nn + z * hold;
        }
    }
}

// ---------------- Set2Set (6 steps) + memory LSTM ----------------
__global__ __launch_bounds__(256) void k_s2s(const float* __restrict__ out,
                                             const float* __restrict__ wT,
                                             const float* __restrict__ bih, const float* __restrict__ bhh,
                                             const float* __restrict__ mT,
                                             const float* __restrict__ mbih, const float* __restrict__ mbhh,
                                             float* __restrict__ dout, float* __restrict__ hx_buf) {
    int g = blockIdx.x;
    int tid = threadIdx.x;
    int w = tid >> 6, lane = tid & 63;
    __shared__ __align__(16) float os[NPG][65];
    __shared__ __align__(16) float q[128];
    __shared__ __align__(16) float hsS[64];
    __shared__ __align__(16) float csS[64];
    __shared__ __align__(16) float aS[NPG];
    __shared__ __align__(16) float gS[256];
    __shared__ __align__(16) float rP[4][64];
    for (int idx = tid; idx < NPG * 64; idx += 256)
        os[idx >> 6][idx & 63] = out[(size_t)(g * NPG) * 64 + idx];
    if (tid < 128) q[tid] = 0.0f;
    if (tid < 64) { hsS[tid] = 0.0f; csS[tid] = 0.0f; }
    float bsum = bih[tid] + bhh[tid];
    __syncthreads();
    const float* wc = wT + tid;
    for (int step = 0; step < 6; ++step) {
        {
            float s0 = 0.f, s1 = 0.f, s2 = 0.f, s3 = 0.f;
#pragma unroll 8
            for (int k = 0; k < 128; k += 4) {
                s0 += q[k]     * wc[(size_t)(k)     * 256];
                s1 += q[k + 1] * wc[(size_t)(k + 1) * 256];
                s2 += q[k + 2] * wc[(size_t)(k + 2) * 256];
                s3 += q[k + 3] * wc[(size_t)(k + 3) * 256];
            }
#pragma unroll 8
            for (int k = 0; k < 64; k += 4) {
                s0 += hsS[k]     * wc[(size_t)(128 + k) * 256];
                s1 += hsS[k + 1] * wc[(size_t)(129 + k) * 256];
                s2 += hsS[k + 2] * wc[(size_t)(130 + k) * 256];
                s3 += hsS[k + 3] * wc[(size_t)(131 + k) * 256];
            }
            gS[tid] = bsum + ((s0 + s1) + (s2 + s3));
        }
        __syncthreads();
        if (tid < 64) {
            float cs = sigmoidf_(gS[64 + tid]) * csS[tid] + sigmoidf_(gS[tid]) * tanhf(gS[128 + tid]);
            csS[tid] = cs;
            hsS[tid] = sigmoidf_(gS[192 + tid]) * tanhf(cs);
        }
        __syncthreads();
        if (w == 0) {
            float e_n = -INFINITY;
            if (lane < NPG) {
                float s = 0.0f;
                for (int h = 0; h < 64; ++h) s += os[lane][h] * hsS[h];
                e_n = s;
            }
            float mx = e_n;
#pragma unroll
            for (int off = 32; off; off >>= 1) mx = fmaxf(mx, __shfl_xor(mx, off));
            float ex = (lane < NPG) ? __expf(e_n - mx) : 0.0f;
            float sm = ex;
#pragma unroll
            for (int off = 32; off; off >>= 1) sm += __shfl_xor(sm, off);
            if (lane < NPG) aS[lane] = ex / sm;
        }
        __syncthreads();
        {
            float r = 0.0f;
            for (int n = w * 10; n < w * 10 + 10; ++n) r += aS[n] * os[n][lane];
            rP[w][lane] = r;
        }
        __syncthreads();
        if (tid < 64) {
            q[tid] = hsS[tid];
            q[64 + tid] = rP[0][tid] + rP[1][tid] + rP[2][tid] + rP[3][tid];
        }
        __syncthreads();
    }
    {
        const float* mc = mT + tid;
        float s0 = 0.f, s1 = 0.f, s2 = 0.f, s3 = 0.f;
#pragma unroll 8
        for (int k = 0; k < 128; k += 4) {
            s0 += q[k]     * mc[(size_t)(k)     * 256];
            s1 += q[k + 1] * mc[(size_t)(k + 1) * 256];
            s2 += q[k + 2] * mc[(size_t)(k + 2) * 256];
            s3 += q[k + 3] * mc[(size_t)(k + 3) * 256];
        }
        gS[tid] = mbih[tid] + mbhh[tid] + ((s0 + s1) + (s2 + s3));
    }
    __syncthreads();
    if (tid < 64) {
        float cx = sigmoidf_(gS[tid]) * tanhf(gS[128 + tid]);
        float hx = sigmoidf_(gS[192 + tid]) * tanhf(cx);
        dout[30000 + g * 64 + tid] = hx;
        dout[62000 + g * 64 + tid] = cx;
        hx_buf[g * 64 + tid] = hx;
    }
}

// ---------------- final MLP over torsions ----------------
__global__ __launch_bounds__(256) void k_mlp(const float* __restrict__ out,
                                             const float* __restrict__ hx_buf,
                                             const int* __restrict__ nrbidx,
                                             const int* __restrict__ nonring,
                                             const float* __restrict__ w1T, const float* __restrict__ b1,
                                             const float* __restrict__ w2, const float* __restrict__ b2,
                                             float* __restrict__ logits) {
    __shared__ __align__(16) float feat[4][320];
    __shared__ __align__(16) float hid[4][64];
    int w = threadIdx.x >> 6, lane = threadIdx.x & 63;
    int t = (blockIdx.x << 2) + w;
    int g = nrbidx[t];
    feat[w][lane] = hx_buf[g * 64 + lane];
#pragma unroll
    for (int i = 0; i < 4; ++i) {
        int node = nonring[t * 4 + i];
        feat[w][64 + i * 64 + lane] = out[(size_t)node * 64 + lane];
    }
    __syncthreads();
    const float* fr = feat[w];
    float s0 = 0.f, s1 = 0.f, s2 = 0.f, s3 = 0.f;
#pragma unroll 8
    for (int i = 0; i < 320; i += 4) {
        s0 += fr[i]     * w1T[(i)     * 64 + lane];
        s1 += fr[i + 1] * w1T[(i + 1) * 64 + lane];
        s2 += fr[i + 2] * w1T[(i + 2) * 64 + lane];
        s3 += fr[i + 3] * w1T[(i + 3) * 64 + lane];
    }
    hid[w][lane] = fmaxf(b1[lane] + ((s0 + s1) + (s2 + s3)), 0.0f);
    __syncthreads();
    if (lane < ACT) {
        const float* hr = hid[w];
        const float* w2r = w2 + lane * 64;
        float s2v = b2[lane];
#pragma unroll 8
        for (int k = 0; k < 64; ++k) s2v += hr[k] * w2r[k];
        logits[t * ACT + lane] = s2v;
    }
}

static inline size_t align256(size_t x) { return (x + 255) & ~(size_t)255; }

extern "C" void kernel_launch(void* const* d_in, const int* in_sizes, int n_in,
                              void* d_out, int out_size, void* d_ws, size_t ws_size,
                              hipStream_t stream) {
    const float* x         = (const float*)d_in[0];
    const float* edge_attr = (const float*)d_in[1];
    const int*   edge_index= (const int*)d_in[2];
    const int*   nrbidx    = (const int*)d_in[4];
    const int*   nonring   = (const int*)d_in[5];
    const float* lin0_w    = (const float*)d_in[6];
    const float* lin0_b    = (const float*)d_in[7];
    const float* enn_w1    = (const float*)d_in[8];
    const float* enn_b1    = (const float*)d_in[9];
    const float* enn_w2    = (const float*)d_in[10];
    const float* enn_b2    = (const float*)d_in[11];
    const float* conv_root = (const float*)d_in[12];
    const float* conv_bias = (const float*)d_in[13];
    const float* gru_wih   = (const float*)d_in[14];
    const float* gru_whh   = (const float*)d_in[15];
    const float* gru_bih   = (const float*)d_in[16];
    const float* gru_bhh   = (const float*)d_in[17];
    const float* s2s_wih   = (const float*)d_in[18];
    const float* s2s_whh   = (const float*)d_in[19];
    const float* s2s_bih   = (const float*)d_in[20];
    const float* s2s_bhh   = (const float*)d_in[21];
    const float* mem_wih   = (const float*)d_in[22];
    const float* mem_bih   = (const float*)d_in[24];
    const float* mem_bhh   = (const float*)d_in[25];
    const float* mlp_w1    = (const float*)d_in[26];
    const float* mlp_b1    = (const float*)d_in[27];
    const float* mlp_w2    = (const float*)d_in[28];
    const float* mlp_b2    = (const float*)d_in[29];
    float* dout = (float*)d_out;

    char* ws = (char*)d_ws;
    size_t off = 0;
    float* out_buf = (float*)(ws + off); off = align256(off + (size_t)N_NODES * 64 * 4);
    float* msg     = (float*)(ws + off); off = align256(off + (size_t)N_EDGES * 64 * 4);
    __hip_bfloat16* h1b  = (__hip_bfloat16*)(ws + off); off = align256(off + (size_t)N_EDGES * 128 * 2);
    __hip_bfloat16* w2pb = (__hip_bfloat16*)(ws + off); off = align256(off + (size_t)4096 * 128 * 2);
    __hip_bfloat16* b2pb = (__hip_bfloat16*)(ws + off); off = align256(off + 4096 * 2);
    int* degi      = (int*)(ws + off); off = align256(off + N_NODES * 4);
    int* rowptr    = (int*)(ws + off); off = align256(off + (N_NODES + 1) * 4);
    int* cursor    = (int*)(ws + off); off = align256(off + N_NODES * 4);
    int* csr       = (int*)(ws + off); off = align256(off + N_EDGES * 4);
    float* hx_buf  = (float*)(ws + off); off = align256(off + (size_t)N_GRAPHS * 64 * 4);
    __hip_bfloat16* wihb = (__hip_bfloat16*)(ws + off); off = align256(off + 192 * 64 * 2);
    __hip_bfloat16* whhb = (__hip_bfloat16*)(ws + off); off = align256(off + 192 * 64 * 2);
    __hip_bfloat16* crTb = (__hip_bfloat16*)(ws + off); off = align256(off + 64 * 64 * 2);
    float* wT      = (float*)(ws + off); off = align256(off + 192 * 256 * 4);
    float* mT      = (float*)(ws + off); off = align256(off + 128 * 256 * 4);
    float* w1T     = (float*)(ws + off); off = align256(off + 320 * 64 * 4);
    if (ws_size < off) return;  // ~29 MB needed

    k_mega_prep<<<(PR_TOTAL + 255) / 256, 256, 0, stream>>>(
        x, lin0_w, lin0_b, edge_attr, enn_w1, enn_b1, enn_w2, enn_b2,
        conv_root, gru_wih, gru_whh, s2s_wih, s2s_whh, mem_wih, mlp_w1,
        out_buf, h1b, w2pb, b2pb, crTb, wihb, whhb, wT, mT, w1T, degi);
    k_deg<<<(N_EDGES + 255) / 256, 256, 0, stream>>>(edge_index, degi);
    k_scan<<<1, 256, 0, stream>>>(degi, rowptr, cursor);
    k_fill<<<(N_EDGES + 255) / 256, 256, 0, stream>>>(edge_index, cursor, csr);
    for (int it = 0; it < 6; ++it) {
        k_edge_msg<<<1024, 256, 0, stream>>>(edge_index, out_buf, h1b, w2pb, b2pb, msg);
        k_node_fused<<<N_NODES / 16, 64, 0, stream>>>(out_buf, rowptr, csr, msg, crTb, conv_bias,
                                                      wihb, whhb, gru_bih, gru_bhh);
    }
    k_s2s<<<N_GRAPHS, 256, 0, stream>>>(out_buf, wT, s2s_bih, s2s_bhh,
                                        mT, mem_bih, mem_bhh, dout, hx_buf);
    k_mlp<<<N_TORS / 4, 256, 0, stream>>>(out_buf, hx_buf, nrbidx, nonring,
                                          w1T, mlp_b1, mlp_w2, mlp_b2, dout);
}

// Round 19
// 705.240 us; speedup vs baseline: 1.1787x; 1.1787x over previous
//
#include <hip/hip_runtime.h>
#include <hip/hip_bf16.h>
#include <stdint.h>

#define N_NODES 20000
#define N_EDGES 40000
#define NODE_DIM 5
#define EDGE_DIM 6
#define HID 64
#define N_GRAPHS 500
#define NPG 40
#define TORSIONS 10
#define N_TORS (N_GRAPHS * TORSIONS)
#define ACT 6

typedef short short8 __attribute__((ext_vector_type(8)));
typedef float f32x4 __attribute__((ext_vector_type(4)));

__device__ __forceinline__ float sigmoidf_(float x) { return 1.0f / (1.0f + __expf(-x)); }
__device__ __forceinline__ float dot4(float4 a, float4 b) {
    return a.x * b.x + a.y * b.y + a.z * b.z + a.w * b.w;
}
__device__ __forceinline__ float bf_lo(unsigned int u) {
    union { unsigned int i; float f; } v; v.i = u << 16; return v.f;
}
__device__ __forceinline__ float bf_hi(unsigned int u) {
    union { unsigned int i; float f; } v; v.i = u & 0xffff0000u; return v.f;
}

// ---------------- fused prologue ----------------
#define PR_LIN0   (N_NODES * 64)
#define PR_H1     (N_EDGES * 128)
#define PR_PREP   (4096 * 128)
#define PR_PREP2  (24576 + 4096)
#define PR_PREP3  (192 * 256 + 128 * 256 + 320 * 64)
#define PR_TOTAL  (PR_LIN0 + PR_H1 + PR_PREP + PR_PREP2 + PR_PREP3 + N_NODES)

__global__ __launch_bounds__(256) void k_mega_prep(
    const float* __restrict__ x, const float* __restrict__ lin0_w, const float* __restrict__ lin0_b,
    const float* __restrict__ ea, const float* __restrict__ enn_w1, const float* __restrict__ enn_b1,
    const float* __restrict__ w2, const float* __restrict__ b2,
    const float* __restrict__ cr, const float* __restrict__ gwih, const float* __restrict__ gwhh,
    const float* __restrict__ swih, const float* __restrict__ swhh,
    const float* __restrict__ mwih, const float* __restrict__ mlpw1,
    float* __restrict__ out, __hip_bfloat16* __restrict__ h1b,
    __hip_bfloat16* __restrict__ w2pb, __hip_bfloat16* __restrict__ b2pb,
    __hip_bfloat16* __restrict__ crTb, __hip_bfloat16* __restrict__ wihb,
    __hip_bfloat16* __restrict__ whhb,
    float* __restrict__ wT, float* __restrict__ mT, float* __restrict__ w1T,
    int* __restrict__ degi) {
    int i = blockIdx.x * blockDim.x + threadIdx.x;
    if (i < PR_LIN0) {
        int n = i >> 6, k = i & 63;
        const float* xr = x + n * NODE_DIM;
        const float* wr = lin0_w + k * NODE_DIM;
        float s = lin0_b[k];
#pragma unroll
        for (int d = 0; d < NODE_DIM; ++d) s += xr[d] * wr[d];
        out[i] = fmaxf(s, 0.0f);
        return;
    }
    i -= PR_LIN0;
    if (i < PR_H1) {
        int e = i >> 7, j = i & 127;
        const float* er = ea + e * EDGE_DIM;
        const float* wr = enn_w1 + j * EDGE_DIM;
        float s = enn_b1[j];
#pragma unroll
        for (int d = 0; d < EDGE_DIM; ++d) s += er[d] * wr[d];
        h1b[i] = __float2bfloat16(fmaxf(s, 0.0f));
        return;
    }
    i -= PR_H1;
    if (i < PR_PREP) {
        int cp = i >> 7, j = i & 127;
        int c = ((cp & 63) << 6) | (cp >> 6);
        w2pb[i] = __float2bfloat16(w2[c * 128 + j]);
        if (j == 0) b2pb[cp] = __float2bfloat16(b2[c]);
        return;
    }
    i -= PR_PREP;
    if (i < PR_PREP2) {
        if (i < 12288) {
            wihb[i] = __float2bfloat16(gwih[i]);
        } else if (i < 24576) {
            whhb[i - 12288] = __float2bfloat16(gwhh[i - 12288]);
        } else {
            int t = i - 24576;
            int c = t >> 6, h = t & 63;
            crTb[t] = __float2bfloat16(cr[h * 64 + c]);
        }
        return;
    }
    i -= PR_PREP2;
    if (i < PR_PREP3) {
        if (i < 192 * 256) {
            int k = i >> 8, j = i & 255;
            wT[i] = (k < 128) ? swih[j * 128 + k] : swhh[j * 64 + (k - 128)];
        } else if (i < 192 * 256 + 128 * 256) {
            int t = i - 192 * 256;
            int k = t >> 8, j = t & 255;
            mT[t] = mwih[j * 128 + k];
        } else {
            int t = i - (192 * 256 + 128 * 256);
            int ii = t >> 6, j = t & 63;
            w1T[t] = mlpw1[j * 320 + ii];
        }
        return;
    }
    i -= PR_PREP3;
    if (i < N_NODES) degi[i] = 0;
}

// ---------------- in-degree ----------------
__global__ void k_deg(const int* __restrict__ ei, int* __restrict__ degi) {
    int e = blockIdx.x * blockDim.x + threadIdx.x;
    if (e >= N_EDGES) return;
    atomicAdd(&degi[ei[N_EDGES + e]], 1);
}

// ---------------- exclusive scan ----------------
#define SCAN_C 79
__global__ __launch_bounds__(256) void k_scan(const int* __restrict__ degi,
                                              int* __restrict__ rowptr, int* __restrict__ cursor) {
    __shared__ int part[256];
    int t = threadIdx.x;
    int base = t * SCAN_C;
    int s = 0;
    for (int i = 0; i < SCAN_C; ++i) {
        int idx = base + i;
        if (idx < N_NODES) s += degi[idx];
    }
    part[t] = s;
    __syncthreads();
    for (int off = 1; off < 256; off <<= 1) {
        int v = (t >= off) ? part[t - off] : 0;
        __syncthreads();
        part[t] += v;
        __syncthreads();
    }
    int run = part[t] - s;
    for (int i = 0; i < SCAN_C; ++i) {
        int idx = base + i;
        if (idx < N_NODES) {
            rowptr[idx] = run;
            cursor[idx] = run;
            run += degi[idx];
        }
    }
    if (t == 0) rowptr[N_NODES] = N_EDGES;
}

// ---------------- CSR fill ----------------
__global__ void k_fill(const int* __restrict__ ei, int* __restrict__ cursor,
                       int* __restrict__ csr) {
    int e = blockIdx.x * blockDim.x + threadIdx.x;
    if (e >= N_EDGES) return;
    int d = ei[N_EDGES + e];
    int pos = atomicAdd(&cursor[d], 1);
    csr[pos] = e;
}

// ---------------- edge messages: kt-paired (wave owns 2 kt), 16 kt per block ----------------
// Round-17 best config. Block = 512 threads (8 waves); kt = kb*16 + w*2 + {0,1}; kb in 0..3;
// grid = 512 (xg = bid&7 -> XCD; kb = (bid>>3)&3; ebg = (bid>>5)*8 + xg, guard >= 125).
// Full-line msg stores (64 B per edge within-block). Sync staging (prefetch regressed 3x).
#define EPB 5
__global__ __launch_bounds__(512) void k_edge_msg(
    const int* __restrict__ ei, const float* __restrict__ out,
    const __hip_bfloat16* __restrict__ h1b, const __hip_bfloat16* __restrict__ w2pb,
    const __hip_bfloat16* __restrict__ b2pb, float* __restrict__ msg) {
    __shared__ __align__(16) short aS[64 * 17 * 8];   // h1 rows, stride 17 short8 (17.4 KB)
    __shared__ __align__(16) float oS[64 * 68];       // o rows, stride 68 f32 (17.4 KB)
    __shared__ __align__(16) float mS[64 * 17];       // msg tile 64e x 16kt, stride 17 (4.4 KB)
    __shared__ __align__(8)  short bS[1024];          // bias slice for this kb (2 KB)
    int bid = blockIdx.x;
    int xg = bid & 7, kb = (bid >> 3) & 3, eg = bid >> 5;
    int ebg = eg * 8 + xg;          // 0..127; guard
    if (ebg >= 125) return;
    int tid = threadIdx.x, w = tid >> 6, lane = tid & 63;
    int lm = lane & 15, lk = lane >> 4;
    const short8* W8 = (const short8*)w2pb;
    short8 afr[2][4][4];
#pragma unroll
    for (int u = 0; u < 2; ++u)
#pragma unroll
        for (int hi = 0; hi < 4; ++hi)
#pragma unroll
            for (int ks = 0; ks < 4; ++ks)
                afr[u][hi][ks] = W8[(size_t)(((kb << 4) + (w << 1) + u) * 64 + hi * 16 + lm) * 16 + ks * 4 + lk];
    bS[tid] = ((const short*)b2pb)[(kb << 10) + tid];
    bS[tid + 512] = ((const short*)b2pb)[(kb << 10) + tid + 512];
    const short8* aSb8 = (const short8*)aS;
    const float4* oS4 = (const float4*)oS;
    for (int t = 0; t < EPB; ++t) {
        int e0 = (ebg * EPB + t) << 6;
        {   // stage h1: 64 rows x 16 uint4, 2 per thread
            const uint4* g = (const uint4*)(h1b + (size_t)e0 * 128);
            uint4* s = (uint4*)aS;
#pragma unroll
            for (int p = 0; p < 2; ++p) {
                int i = tid + 512 * p;
                s[(i >> 4) * 17 + (i & 15)] = g[i];
            }
        }
        {   // gather out[src]: 64 rows x 16 float4, 2 per thread
            const float4* og = (const float4*)out;
            float4* s = (float4*)oS;
#pragma unroll
            for (int p = 0; p < 2; ++p) {
                int i = tid + 512 * p;
                int src = ei[e0 + (i >> 4)];
                s[(i >> 4) * 17 + (i & 15)] = og[(size_t)src * 16 + (i & 15)];
            }
        }
        __syncthreads();
#pragma unroll
        for (int ee = 0; ee < 4; ++ee) {
            short8 bfr[4];
#pragma unroll
            for (int ks = 0; ks < 4; ++ks) bfr[ks] = aSb8[(ee * 16 + lm) * 17 + ks * 4 + lk];
            float4 ofr[4];
#pragma unroll
            for (int hi = 0; hi < 4; ++hi) ofr[hi] = oS4[(ee * 16 + lm) * 17 + hi * 4 + lk];
            float pk[2] = {0.0f, 0.0f};
#pragma unroll
            for (int u = 0; u < 2; ++u) {
#pragma unroll
                for (int hi = 0; hi < 4; ++hi) {
                    f32x4 a0 = (f32x4){0.f, 0.f, 0.f, 0.f};
                    f32x4 a1 = (f32x4){0.f, 0.f, 0.f, 0.f};
                    a0 = __builtin_amdgcn_mfma_f32_16x16x32_bf16(afr[u][hi][0], bfr[0], a0, 0, 0, 0);
                    a1 = __builtin_amdgcn_mfma_f32_16x16x32_bf16(afr[u][hi][1], bfr[1], a1, 0, 0, 0);
                    a0 = __builtin_amdgcn_mfma_f32_16x16x32_bf16(afr[u][hi][2], bfr[2], a0, 0, 0, 0);
                    a1 = __builtin_amdgcn_mfma_f32_16x16x32_bf16(afr[u][hi][3], bfr[3], a1, 0, 0, 0);
                    uint2 bp = *(const uint2*)(bS + ((w << 1) + u) * 64 + hi * 16 + lk * 4);
                    pk[u] += (a0[0] + a1[0] + bf_lo(bp.x)) * ofr[hi].x +
                             (a0[1] + a1[1] + bf_hi(bp.x)) * ofr[hi].y +
                             (a0[2] + a1[2] + bf_lo(bp.y)) * ofr[hi].z +
                             (a0[3] + a1[3] + bf_hi(bp.y)) * ofr[hi].w;
                }
                pk[u] += __shfl_xor(pk[u], 16);
                pk[u] += __shfl_xor(pk[u], 32);
            }
            if (lane < 16) {
                mS[(ee * 16 + lane) * 17 + (w << 1)]     = pk[0];
                mS[(ee * 16 + lane) * 17 + (w << 1) + 1] = pk[1];
            }
        }
        __syncthreads();
        {   // cooperative store: 64 edges x 16 kt, 2 per thread; 16 threads = 64 B full line
#pragma unroll
            for (int p = 0; p < 2; ++p) {
                int idx = tid + 512 * p;
                int e = idx >> 4, kl = idx & 15;
                msg[(size_t)(e0 + e) * 64 + (kb << 4) + kl] = mS[e * 17 + kl];
            }
        }
    }
}

// ---------------- fused node update: CSR-agg + root GEMM + m + GRU; 1 wave = 16 nodes ----------------
__global__ __launch_bounds__(64) void k_node_fused(
    float* __restrict__ out,
    const int* __restrict__ rowptr, const int* __restrict__ csr, const float* __restrict__ msg,
    const __hip_bfloat16* __restrict__ crTb, const float* __restrict__ cb,
    const __hip_bfloat16* __restrict__ wihb, const __hip_bfloat16* __restrict__ whhb,
    const float* __restrict__ bih, const float* __restrict__ bhh) {
    __shared__ __align__(16) float Xf[16 * 68];
    __shared__ __align__(16) short Xb[16 * 72];
    __shared__ __align__(16) short Mb[16 * 72];
    int n0 = blockIdx.x << 4;
    int lane = threadIdx.x;
    {
        int r = lane >> 2, q = lane & 3;
        const float4* gv = (const float4*)(out + (size_t)(n0 + r) * 64);
        float4 v[4];
#pragma unroll
        for (int i = 0; i < 4; ++i) v[i] = gv[q * 4 + i];
        float4* sv = (float4*)Xf;
#pragma unroll
        for (int i = 0; i < 4; ++i) sv[r * 17 + q * 4 + i] = v[i];
        __hip_bfloat16* xb = (__hip_bfloat16*)Xb;
        const float* vf = (const float*)v;
#pragma unroll
        for (int i = 0; i < 16; ++i) xb[r * 72 + q * 16 + i] = __float2bfloat16(vf[i]);
    }
    __syncthreads();
    int lm = lane & 15, lk = lane >> 4;
    const short8* Xb8 = (const short8*)Xb;
    short8 ax[2];
#pragma unroll
    for (int ks = 0; ks < 2; ++ks) ax[ks] = Xb8[lm * 9 + ks * 4 + lk];
    const short8* Bc = (const short8*)crTb;
    f32x4 accr[4];
#pragma unroll
    for (int ci = 0; ci < 4; ++ci) accr[ci] = (f32x4){0.f, 0.f, 0.f, 0.f};
#pragma unroll
    for (int ks = 0; ks < 2; ++ks)
#pragma unroll
        for (int ci = 0; ci < 4; ++ci) {
            short8 b = Bc[(ci * 16 + lm) * 8 + ks * 4 + lk];
            accr[ci] = __builtin_amdgcn_mfma_f32_16x16x32_bf16(ax[ks], b, accr[ci], 0, 0, 0);
        }
    float aost[4][4];  // [j][ci]
#pragma unroll
    for (int j = 0; j < 4; ++j) {
        int n = n0 + lk * 4 + j;
        int b = rowptr[n], e_ = rowptr[n + 1];
        float s0 = 0.f, s1 = 0.f, s2 = 0.f, s3 = 0.f;
        for (int i = b; i < e_; ++i) {
            const float* mrow = msg + (size_t)csr[i] * 64;
            s0 += mrow[lm];
            s1 += mrow[16 + lm];
            s2 += mrow[32 + lm];
            s3 += mrow[48 + lm];
        }
        float inv = 1.0f / fmaxf((float)(e_ - b), 1.0f);
        aost[j][0] = s0 * inv; aost[j][1] = s1 * inv; aost[j][2] = s2 * inv; aost[j][3] = s3 * inv;
    }
    __hip_bfloat16* mb = (__hip_bfloat16*)Mb;
#pragma unroll
    for (int ci = 0; ci < 4; ++ci) {
        int col = ci * 16 + lm;
        float cbv = cb[col];
#pragma unroll
        for (int j = 0; j < 4; ++j) {
            int row = lk * 4 + j;
            float m = fmaxf(aost[j][ci] + accr[ci][j] + cbv, 0.f);
            mb[row * 72 + col] = __float2bfloat16(m);
        }
    }
    __syncthreads();
    short8 am[2];
#pragma unroll
    for (int ks = 0; ks < 2; ++ks) am[ks] = ((const short8*)Mb)[lm * 9 + ks * 4 + lk];
    const short8* Bi = (const short8*)wihb;
    const short8* Bh = (const short8*)whhb;
    f32x4 gi[12], gh[12];
#pragma unroll
    for (int ci = 0; ci < 12; ++ci) {
        gi[ci] = (f32x4){0.f, 0.f, 0.f, 0.f};
        gh[ci] = (f32x4){0.f, 0.f, 0.f, 0.f};
    }
#pragma unroll
    for (int ks = 0; ks < 2; ++ks)
#pragma unroll
        for (int ci = 0; ci < 12; ++ci) {
            short8 bi = Bi[(ci * 16 + lm) * 8 + ks * 4 + lk];
            short8 bh = Bh[(ci * 16 + lm) * 8 + ks * 4 + lk];
            gi[ci] = __builtin_amdgcn_mfma_f32_16x16x32_bf16(am[ks], bi, gi[ci], 0, 0, 0);
            gh[ci] = __builtin_amdgcn_mfma_f32_16x16x32_bf16(ax[ks], bh, gh[ci], 0, 0, 0);
        }
#pragma unroll
    for (int ci = 0; ci < 4; ++ci) {
        int col = ci * 16 + lm;
        float bir = bih[col], biz = bih[64 + col], bin = bih[128 + col];
        float bhr = bhh[col], bhz = bhh[64 + col], bhn = bhh[128 + col];
#pragma unroll
        for (int j = 0; j < 4; ++j) {
            int row = lk * 4 + j;
            int n = n0 + row;
            float r = sigmoidf_(gi[ci][j] + bir + gh[ci][j] + bhr);
            float z = sigmoidf_(gi[ci + 4][j] + biz + gh[ci + 4][j] + bhz);
            float nn = tanhf(gi[ci + 8][j] + bin + r * (gh[ci + 8][j] + bhn));
            float hold = Xf[row * 68 + col];
            out[(size_t)n * 64 + col] = (1.f - z) * nn + z * hold;
        }
    }
}

// ---------------- Set2Set (6 steps) + memory LSTM ----------------
__global__ __launch_bounds__(256) void k_s2s(const float* __restrict__ out,
                                             const float* __restrict__ wT,
                                             const float* __restrict__ bih, const float* __restrict__ bhh,
                                             const float* __restrict__ mT,
                                             const float* __restrict__ mbih, const float* __restrict__ mbhh,
                                             float* __restrict__ dout, float* __restrict__ hx_buf) {
    int g = blockIdx.x;
    int tid = threadIdx.x;
    int w = tid >> 6, lane = tid & 63;
    __shared__ __align__(16) float os[NPG][65];
    __shared__ __align__(16) float q[128];
    __shared__ __align__(16) float hsS[64];
    __shared__ __align__(16) float csS[64];
    __shared__ __align__(16) float aS[NPG];
    __shared__ __align__(16) float gS[256];
    __shared__ __align__(16) float rP[4][64];
    for (int idx = tid; idx < NPG * 64; idx += 256)
        os[idx >> 6][idx & 63] = out[(size_t)(g * NPG) * 64 + idx];
    if (tid < 128) q[tid] = 0.0f;
    if (tid < 64) { hsS[tid] = 0.0f; csS[tid] = 0.0f; }
    float bsum = bih[tid] + bhh[tid];
    __syncthreads();
    const float* wc = wT + tid;
    for (int step = 0; step < 6; ++step) {
        {
            float s0 = 0.f, s1 = 0.f, s2 = 0.f, s3 = 0.f;
#pragma unroll 8
            for (int k = 0; k < 128; k += 4) {
                s0 += q[k]     * wc[(size_t)(k)     * 256];
                s1 += q[k + 1] * wc[(size_t)(k + 1) * 256];
                s2 += q[k + 2] * wc[(size_t)(k + 2) * 256];
                s3 += q[k + 3] * wc[(size_t)(k + 3) * 256];
            }
#pragma unroll 8
            for (int k = 0; k < 64; k += 4) {
                s0 += hsS[k]     * wc[(size_t)(128 + k) * 256];
                s1 += hsS[k + 1] * wc[(size_t)(129 + k) * 256];
                s2 += hsS[k + 2] * wc[(size_t)(130 + k) * 256];
                s3 += hsS[k + 3] * wc[(size_t)(131 + k) * 256];
            }
            gS[tid] = bsum + ((s0 + s1) + (s2 + s3));
        }
        __syncthreads();
        if (tid < 64) {
            float cs = sigmoidf_(gS[64 + tid]) * csS[tid] + sigmoidf_(gS[tid]) * tanhf(gS[128 + tid]);
            csS[tid] = cs;
            hsS[tid] = sigmoidf_(gS[192 + tid]) * tanhf(cs);
        }
        __syncthreads();
        if (w == 0) {
            float e_n = -INFINITY;
            if (lane < NPG) {
                float s = 0.0f;
                for (int h = 0; h < 64; ++h) s += os[lane][h] * hsS[h];
                e_n = s;
            }
            float mx = e_n;
#pragma unroll
            for (int off = 32; off; off >>= 1) mx = fmaxf(mx, __shfl_xor(mx, off));
            float ex = (lane < NPG) ? __expf(e_n - mx) : 0.0f;
            float sm = ex;
#pragma unroll
            for (int off = 32; off; off >>= 1) sm += __shfl_xor(sm, off);
            if (lane < NPG) aS[lane] = ex / sm;
        }
        __syncthreads();
        {
            float r = 0.0f;
            for (int n = w * 10; n < w * 10 + 10; ++n) r += aS[n] * os[n][lane];
            rP[w][lane] = r;
        }
        __syncthreads();
        if (tid < 64) {
            q[tid] = hsS[tid];
            q[64 + tid] = rP[0][tid] + rP[1][tid] + rP[2][tid] + rP[3][tid];
        }
        __syncthreads();
    }
    {
        const float* mc = mT + tid;
        float s0 = 0.f, s1 = 0.f, s2 = 0.f, s3 = 0.f;
#pragma unroll 8
        for (int k = 0; k < 128; k += 4) {
            s0 += q[k]     * mc[(size_t)(k)     * 256];
            s1 += q[k + 1] * mc[(size_t)(k + 1) * 256];
            s2 += q[k + 2] * mc[(size_t)(k + 2) * 256];
            s3 += q[k + 3] * mc[(size_t)(k + 3) * 256];
        }
        gS[tid] = mbih[tid] + mbhh[tid] + ((s0 + s1) + (s2 + s3));
    }
    __syncthreads();
    if (tid < 64) {
        float cx = sigmoidf_(gS[tid]) * tanhf(gS[128 + tid]);
        float hx = sigmoidf_(gS[192 + tid]) * tanhf(cx);
        dout[30000 + g * 64 + tid] = hx;
        dout[62000 + g * 64 + tid] = cx;
        hx_buf[g * 64 + tid] = hx;
    }
}

// ---------------- final MLP over torsions ----------------
__global__ __launch_bounds__(256) void k_mlp(const float* __restrict__ out,
                                             const float* __restrict__ hx_buf,
                                             const int* __restrict__ nrbidx,
                                             const int* __restrict__ nonring,
                                             const float* __restrict__ w1T, const float* __restrict__ b1,
                                             const float* __restrict__ w2, const float* __restrict__ b2,
                                             float* __restrict__ logits) {
    __shared__ __align__(16) float feat[4][320];
    __shared__ __align__(16) float hid[4][64];
    int w = threadIdx.x >> 6, lane = threadIdx.x & 63;
    int t = (blockIdx.x << 2) + w;
    int g = nrbidx[t];
    feat[w][lane] = hx_buf[g * 64 + lane];
#pragma unroll
    for (int i = 0; i < 4; ++i) {
        int node = nonring[t * 4 + i];
        feat[w][64 + i * 64 + lane] = out[(size_t)node * 64 + lane];
    }
    __syncthreads();
    const float* fr = feat[w];
    float s0 = 0.f, s1 = 0.f, s2 = 0.f, s3 = 0.f;
#pragma unroll 8
    for (int i = 0; i < 320; i += 4) {
        s0 += fr[i]     * w1T[(i)     * 64 + lane];
        s1 += fr[i + 1] * w1T[(i + 1) * 64 + lane];
        s2 += fr[i + 2] * w1T[(i + 2) * 64 + lane];
        s3 += fr[i + 3] * w1T[(i + 3) * 64 + lane];
    }
    hid[w][lane] = fmaxf(b1[lane] + ((s0 + s1) + (s2 + s3)), 0.0f);
    __syncthreads();
    if (lane < ACT) {
        const float* hr = hid[w];
        const float* w2r = w2 + lane * 64;
        float s2v = b2[lane];
#pragma unroll 8
        for (int k = 0; k < 64; ++k) s2v += hr[k] * w2r[k];
        logits[t * ACT + lane] = s2v;
    }
}

static inline size_t align256(size_t x) { return (x + 255) & ~(size_t)255; }

extern "C" void kernel_launch(void* const* d_in, const int* in_sizes, int n_in,
                              void* d_out, int out_size, void* d_ws, size_t ws_size,
                              hipStream_t stream) {
    const float* x         = (const float*)d_in[0];
    const float* edge_attr = (const float*)d_in[1];
    const int*   edge_index= (const int*)d_in[2];
    const int*   nrbidx    = (const int*)d_in[4];
    const int*   nonring   = (const int*)d_in[5];
    const float* lin0_w    = (const float*)d_in[6];
    const float* lin0_b    = (const float*)d_in[7];
    const float* enn_w1    = (const float*)d_in[8];
    const float* enn_b1    = (const float*)d_in[9];
    const float* enn_w2    = (const float*)d_in[10];
    const float* enn_b2    = (const float*)d_in[11];
    const float* conv_root = (const float*)d_in[12];
    const float* conv_bias = (const float*)d_in[13];
    const float* gru_wih   = (const float*)d_in[14];
    const float* gru_whh   = (const float*)d_in[15];
    const float* gru_bih   = (const float*)d_in[16];
    const float* gru_bhh   = (const float*)d_in[17];
    const float* s2s_wih   = (const float*)d_in[18];
    const float* s2s_whh   = (const float*)d_in[19];
    const float* s2s_bih   = (const float*)d_in[20];
    const float* s2s_bhh   = (const float*)d_in[21];
    const float* mem_wih   = (const float*)d_in[22];
    const float* mem_bih   = (const float*)d_in[24];
    const float* mem_bhh   = (const float*)d_in[25];
    const float* mlp_w1    = (const float*)d_in[26];
    const float* mlp_b1    = (const float*)d_in[27];
    const float* mlp_w2    = (const float*)d_in[28];
    const float* mlp_b2    = (const float*)d_in[29];
    float* dout = (float*)d_out;

    char* ws = (char*)d_ws;
    size_t off = 0;
    float* out_buf = (float*)(ws + off); off = align256(off + (size_t)N_NODES * 64 * 4);
    float* msg     = (float*)(ws + off); off = align256(off + (size_t)N_EDGES * 64 * 4);
    __hip_bfloat16* h1b  = (__hip_bfloat16*)(ws + off); off = align256(off + (size_t)N_EDGES * 128 * 2);
    __hip_bfloat16* w2pb = (__hip_bfloat16*)(ws + off); off = align256(off + (size_t)4096 * 128 * 2);
    __hip_bfloat16* b2pb = (__hip_bfloat16*)(ws + off); off = align256(off + 4096 * 2);
    int* degi      = (int*)(ws + off); off = align256(off + N_NODES * 4);
    int* rowptr    = (int*)(ws + off); off = align256(off + (N_NODES + 1) * 4);
    int* cursor    = (int*)(ws + off); off = align256(off + N_NODES * 4);
    int* csr       = (int*)(ws + off); off = align256(off + N_EDGES * 4);
    float* hx_buf  = (float*)(ws + off); off = align256(off + (size_t)N_GRAPHS * 64 * 4);
    __hip_bfloat16* wihb = (__hip_bfloat16*)(ws + off); off = align256(off + 192 * 64 * 2);
    __hip_bfloat16* whhb = (__hip_bfloat16*)(ws + off); off = align256(off + 192 * 64 * 2);
    __hip_bfloat16* crTb = (__hip_bfloat16*)(ws + off); off = align256(off + 64 * 64 * 2);
    float* wT      = (float*)(ws + off); off = align256(off + 192 * 256 * 4);
    float* mT      = (float*)(ws + off); off = align256(off + 128 * 256 * 4);
    float* w1T     = (float*)(ws + off); off = align256(off + 320 * 64 * 4);
    if (ws_size < off) return;  // ~29 MB needed

    k_mega_prep<<<(PR_TOTAL + 255) / 256, 256, 0, stream>>>(
        x, lin0_w, lin0_b, edge_attr, enn_w1, enn_b1, enn_w2, enn_b2,
        conv_root, gru_wih, gru_whh, s2s_wih, s2s_whh, mem_wih, mlp_w1,
        out_buf, h1b, w2pb, b2pb, crTb, wihb, whhb, wT, mT, w1T, degi);
    k_deg<<<(N_EDGES + 255) / 256, 256, 0, stream>>>(edge_index, degi);
    k_scan<<<1, 256, 0, stream>>>(degi, rowptr, cursor);
    k_fill<<<(N_EDGES + 255) / 256, 256, 0, stream>>>(edge_index, cursor, csr);
    for (int it = 0; it < 6; ++it) {
        k_edge_msg<<<512, 512, 0, stream>>>(edge_index, out_buf, h1b, w2pb, b2pb, msg);
        k_node_fused<<<N_NODES / 16, 64, 0, stream>>>(out_buf, rowptr, csr, msg, crTb, conv_bias,
                                                      wihb, whhb, gru_bih, gru_bhh);
    }
    k_s2s<<<N_GRAPHS, 256, 0, stream>>>(out_buf, wT, s2s_bih, s2s_bhh,
                                        mT, mem_bih, mem_bhh, dout, hx_buf);
    k_mlp<<<N_TORS / 4, 256, 0, stream>>>(out_buf, hx_buf, nrbidx, nonring,
                                          w1T, mlp_b1, mlp_w2, mlp_b2, dout);
}